// Round 1
// baseline (9293.235 us; speedup 1.0000x reference)
//
#include <hip/hip_runtime.h>
#include <math.h>

#define NTHR 1024
#define MB   2
#define ROWS 32          // MB*16 rows per block
#define A_LD 416         // multiple of 32 dwords; XOR-swizzled columns
#define RU_LD 260
#define H_LD  132

__device__ __forceinline__ float sigm(float x) { return 1.0f / (1.0f + __expf(-x)); }

// 8-col gate GEMM: acc[8] += A_row[k] * W[k][n0..n0+7], W leading dim 256
template<int K>
__device__ __forceinline__ void gemm8(const float* __restrict__ Arow, int swz,
                                      const float* __restrict__ Wp, float acc[8]) {
#pragma unroll 2
    for (int k0 = 0; k0 < K; k0 += 4) {
        const float4 a4 = *(const float4*)(Arow + (k0 ^ swz));
        float av[4] = {a4.x, a4.y, a4.z, a4.w};
#pragma unroll
        for (int kk = 0; kk < 4; ++kk) {
            const float4 w0 = *(const float4*)(Wp + (size_t)(k0 + kk) * 256);
            const float4 w1 = *(const float4*)(Wp + (size_t)(k0 + kk) * 256 + 4);
            float a = av[kk];
            acc[0] += a * w0.x; acc[1] += a * w0.y; acc[2] += a * w0.z; acc[3] += a * w0.w;
            acc[4] += a * w1.x; acc[5] += a * w1.y; acc[6] += a * w1.z; acc[7] += a * w1.w;
        }
    }
}

// 4-col candidate GEMM: acc[4] += A_row[k] * W[k][n0..n0+3], W leading dim 128
template<int K>
__device__ __forceinline__ void gemm4(const float* __restrict__ Arow, int swz,
                                      const float* __restrict__ Wp, float acc[4]) {
#pragma unroll 2
    for (int k0 = 0; k0 < K; k0 += 4) {
        const float4 a4 = *(const float4*)(Arow + (k0 ^ swz));
        float av[4] = {a4.x, a4.y, a4.z, a4.w};
#pragma unroll
        for (int kk = 0; kk < 4; ++kk) {
            const float4 w = *(const float4*)(Wp + (size_t)(k0 + kk) * 128);
            float a = av[kk];
            acc[0] += a * w.x; acc[1] += a * w.y; acc[2] += a * w.z; acc[3] += a * w.w;
        }
    }
}

__global__ __launch_bounds__(NTHR) void tgcn_kernel(
    const float* __restrict__ feat,  // [B,5,16,256]
    const float* __restrict__ adj,   // [16,16]
    const float* __restrict__ w1g,   // [384,256]
    const float* __restrict__ b1g,   // [256]
    const float* __restrict__ w1c,   // [384,128]
    const float* __restrict__ w2g,   // [256,256]
    const float* __restrict__ b2g,   // [256]
    const float* __restrict__ w2c,   // [256,128]
    const float* __restrict__ bng, const float* __restrict__ bnb,
    const float* __restrict__ bnm, const float* __restrict__ bnv,
    const float* __restrict__ fcw,   // [2048,2]
    const float* __restrict__ fcb,   // [2]
    float* __restrict__ out)         // [B,2]
{
    __shared__ float A[ROWS * A_LD];     // agg buffer [Lx | Lh], swizzled cols
    __shared__ float RU[ROWS * RU_LD];   // aliased: x-stage, then sigmoid(gates)
    __shared__ float h1s[ROWS * H_LD];
    __shared__ float h2s[ROWS * H_LD];
    __shared__ float Ls[16 * 17];
    __shared__ float dsh[16];
    __shared__ float red[32];

    const int tid = threadIdx.x;
    const int b0  = blockIdx.x * MB;

    // ---- Laplacian: L[i][j] = (adj[j][i] + (i==j)) * d[i] * d[j], d = rowsum(adj+I)^-1/2
    if (tid < 16) {
        float rs = 1.0f;
        for (int j = 0; j < 16; ++j) rs += adj[tid * 16 + j];
        dsh[tid] = 1.0f / sqrtf(rs);
    }
    for (int i = tid; i < ROWS * H_LD; i += NTHR) { h1s[i] = 0.0f; h2s[i] = 0.0f; }
    __syncthreads();
    if (tid < 256) {
        int i = tid >> 4, j = tid & 15;
        float aji = adj[j * 16 + i] + (i == j ? 1.0f : 0.0f);
        Ls[i * 17 + j] = aji * dsh[i] * dsh[j];
    }
    __syncthreads();

    const int r   = tid & 31;     // output row 0..31 (bb*16 + node)
    const int bb  = r >> 4;
    const int an  = r & 15;
    const int ng  = tid >> 5;     // 0..31
    const int swz = (r & 7) << 2; // A-buffer column swizzle for this row

    for (int t = 0; t < 5; ++t) {
        // ---- stage x_t tile into RU (as XS): 32 rows x 256 cols
#pragma unroll
        for (int p = 0; p < 2; ++p) {
            int q = tid + p * NTHR;            // float4 index 0..2047
            int row = q >> 6;
            int c4 = (q & 63) << 2;
            size_t gi = ((((size_t)(b0 + (row >> 4))) * 5 + t) * 16 + (row & 15)) * 256 + c4;
            *(float4*)&RU[row * RU_LD + c4] = *(const float4*)&feat[gi];
        }
        __syncthreads();
        // ---- A[:,0:256] = L @ x ; A[:,256:384] = L @ h1
#pragma unroll
        for (int p = 0; p < 3; ++p) {
            int q = tid + p * NTHR;            // 0..3071
            int rr = q & 31, cq = q >> 5;      // cq 0..95
            int aa = rr & 15, bx = (rr >> 4) * 16;
            int sw = (rr & 7) << 2;
            float4 acc = {0, 0, 0, 0};
            if (cq < 64) {
                int c = cq << 2;
#pragma unroll
                for (int j = 0; j < 16; ++j) {
                    float l = Ls[aa * 17 + j];
                    const float4 v = *(const float4*)&RU[(bx + j) * RU_LD + c];
                    acc.x += l * v.x; acc.y += l * v.y; acc.z += l * v.z; acc.w += l * v.w;
                }
                *(float4*)&A[rr * A_LD + (c ^ sw)] = acc;
            } else {
                int c = (cq - 64) << 2;
#pragma unroll
                for (int j = 0; j < 16; ++j) {
                    float l = Ls[aa * 17 + j];
                    const float4 v = *(const float4*)&h1s[(bx + j) * H_LD + c];
                    acc.x += l * v.x; acc.y += l * v.y; acc.z += l * v.z; acc.w += l * v.w;
                }
                *(float4*)&A[rr * A_LD + ((256 + c) ^ sw)] = acc;
            }
        }
        __syncthreads();
        // ---- gates1: RU = sigmoid(A @ w1g + b1g), K=384, N=256
        {
            float acc[8] = {0, 0, 0, 0, 0, 0, 0, 0};
            int n0 = ng * 8;
            gemm8<384>(A + r * A_LD, swz, w1g + n0, acc);
#pragma unroll
            for (int i = 0; i < 8; ++i)
                RU[r * RU_LD + n0 + i] = sigm(acc[i] + b1g[n0 + i]);
        }
        __syncthreads();
        // ---- A[:,256:384] = L @ (r ⊙ h1)
        {
            int cq = ng;                       // 0..31
            int c = cq << 2;
            int bx = bb * 16;
            float4 acc = {0, 0, 0, 0};
#pragma unroll
            for (int j = 0; j < 16; ++j) {
                float l = Ls[an * 17 + j];
                const float4 rv = *(const float4*)&RU[(bx + j) * RU_LD + c];
                const float4 hv = *(const float4*)&h1s[(bx + j) * H_LD + c];
                acc.x += l * rv.x * hv.x; acc.y += l * rv.y * hv.y;
                acc.z += l * rv.z * hv.z; acc.w += l * rv.w * hv.w;
            }
            *(float4*)&A[r * A_LD + ((256 + c) ^ swz)] = acc;
        }
        __syncthreads();
        // ---- cand1 + h1 update: c = tanh(A @ w1c); h1 = u*h1 + (1-u)*c
        {
            float acc[4] = {0, 0, 0, 0};
            int n0 = ng * 4;
            gemm4<384>(A + r * A_LD, swz, w1c + n0, acc);
#pragma unroll
            for (int i = 0; i < 4; ++i) {
                float c = tanhf(acc[i]);
                float u = RU[r * RU_LD + 128 + n0 + i];
                float h = h1s[r * H_LD + n0 + i];
                h1s[r * H_LD + n0 + i] = u * h + (1.0f - u) * c;
            }
        }
        __syncthreads();
        // ---- cell2 agg: A[:,0:128] = L @ h1, A[:,128:256] = L @ h2
#pragma unroll
        for (int p = 0; p < 2; ++p) {
            int q = tid + p * NTHR;            // 0..2047
            int rr = q & 31, cq = q >> 5;      // 0..63
            int aa = rr & 15, bx = (rr >> 4) * 16;
            int sw = (rr & 7) << 2;
            const float* src = (cq < 32) ? h1s : h2s;
            int c = (cq & 31) << 2;
            int dst = (cq < 32) ? c : (128 + c);
            float4 acc = {0, 0, 0, 0};
#pragma unroll
            for (int j = 0; j < 16; ++j) {
                float l = Ls[aa * 17 + j];
                const float4 v = *(const float4*)&src[(bx + j) * H_LD + c];
                acc.x += l * v.x; acc.y += l * v.y; acc.z += l * v.z; acc.w += l * v.w;
            }
            *(float4*)&A[rr * A_LD + (dst ^ sw)] = acc;
        }
        __syncthreads();
        // ---- gates2: RU = sigmoid(A @ w2g + b2g), K=256
        {
            float acc[8] = {0, 0, 0, 0, 0, 0, 0, 0};
            int n0 = ng * 8;
            gemm8<256>(A + r * A_LD, swz, w2g + n0, acc);
#pragma unroll
            for (int i = 0; i < 8; ++i)
                RU[r * RU_LD + n0 + i] = sigm(acc[i] + b2g[n0 + i]);
        }
        __syncthreads();
        // ---- A[:,128:256] = L @ (r2 ⊙ h2)
        {
            int c = ng << 2;
            int bx = bb * 16;
            float4 acc = {0, 0, 0, 0};
#pragma unroll
            for (int j = 0; j < 16; ++j) {
                float l = Ls[an * 17 + j];
                const float4 rv = *(const float4*)&RU[(bx + j) * RU_LD + c];
                const float4 hv = *(const float4*)&h2s[(bx + j) * H_LD + c];
                acc.x += l * rv.x * hv.x; acc.y += l * rv.y * hv.y;
                acc.z += l * rv.z * hv.z; acc.w += l * rv.w * hv.w;
            }
            *(float4*)&A[r * A_LD + ((128 + c) ^ swz)] = acc;
        }
        __syncthreads();
        // ---- cand2 + h2 update
        {
            float acc[4] = {0, 0, 0, 0};
            int n0 = ng * 4;
            gemm4<256>(A + r * A_LD, swz, w2c + n0, acc);
#pragma unroll
            for (int i = 0; i < 4; ++i) {
                float c = tanhf(acc[i]);
                float u = RU[r * RU_LD + 128 + n0 + i];
                float h = h2s[r * H_LD + n0 + i];
                h2s[r * H_LD + n0 + i] = u * h + (1.0f - u) * c;
            }
        }
        __syncthreads();
    }

    // ---- head: BN -> ReLU -> FC(2048 -> 2), per batch element
    {
        int bh = tid >> 9;          // 0..1
        int s  = tid & 511;
        int k  = s << 2;            // 0..2044
        int a  = k >> 7, c = k & 127;
        const float4 v  = *(const float4*)&h2s[(bh * 16 + a) * H_LD + c];
        const float4 g  = *(const float4*)&bng[k];
        const float4 be = *(const float4*)&bnb[k];
        const float4 mu = *(const float4*)&bnm[k];
        const float4 va = *(const float4*)&bnv[k];
        float x0 = fmaxf(g.x * (v.x - mu.x) * rsqrtf(va.x + 1e-5f) + be.x, 0.0f);
        float x1 = fmaxf(g.y * (v.y - mu.y) * rsqrtf(va.y + 1e-5f) + be.y, 0.0f);
        float x2 = fmaxf(g.z * (v.z - mu.z) * rsqrtf(va.z + 1e-5f) + be.z, 0.0f);
        float x3 = fmaxf(g.w * (v.w - mu.w) * rsqrtf(va.w + 1e-5f) + be.w, 0.0f);
        const float4 w01 = *(const float4*)&fcw[k * 2];
        const float4 w23 = *(const float4*)&fcw[k * 2 + 4];
        float p0 = x0 * w01.x + x1 * w01.z + x2 * w23.x + x3 * w23.z;
        float p1 = x0 * w01.y + x1 * w01.w + x2 * w23.y + x3 * w23.w;
#pragma unroll
        for (int off = 32; off > 0; off >>= 1) {
            p0 += __shfl_down(p0, off);
            p1 += __shfl_down(p1, off);
        }
        int wv = tid >> 6;
        if ((tid & 63) == 0) { red[wv * 2] = p0; red[wv * 2 + 1] = p1; }
        __syncthreads();
        if (tid < 4) {
            int bo = tid >> 1, o = tid & 1;
            float sres = fcb[o];
#pragma unroll
            for (int w = 0; w < 8; ++w) sres += red[(bo * 8 + w) * 2 + o];
            out[(size_t)(b0 + bo) * 2 + o] = sres;
        }
    }
}

extern "C" void kernel_launch(void* const* d_in, const int* in_sizes, int n_in,
                              void* d_out, int out_size, void* d_ws, size_t ws_size,
                              hipStream_t stream) {
    const float* feat = (const float*)d_in[0];
    const float* adj  = (const float*)d_in[1];
    const float* w1g  = (const float*)d_in[2];
    const float* b1g  = (const float*)d_in[3];
    const float* w1c  = (const float*)d_in[4];
    const float* w2g  = (const float*)d_in[5];
    const float* b2g  = (const float*)d_in[6];
    const float* w2c  = (const float*)d_in[7];
    const float* bng  = (const float*)d_in[8];
    const float* bnb  = (const float*)d_in[9];
    const float* bnm  = (const float*)d_in[10];
    const float* bnv  = (const float*)d_in[11];
    const float* fcw  = (const float*)d_in[12];
    const float* fcb  = (const float*)d_in[13];
    float* out = (float*)d_out;

    int B = in_sizes[0] / (5 * 16 * 256);   // 4096
    dim3 grid(B / MB), block(NTHR);
    hipLaunchKernelGGL(tgcn_kernel, grid, block, 0, stream,
                       feat, adj, w1g, b1g, w1c, w2g, b2g, w2c,
                       bng, bnb, bnm, bnv, fcw, fcb, out);
}

// Round 2
// 3170.791 us; speedup vs baseline: 2.9309x; 2.9309x over previous
//
#include <hip/hip_runtime.h>
#include <math.h>

typedef __attribute__((ext_vector_type(8))) short bf8;
typedef __attribute__((ext_vector_type(4))) float f32x4;
typedef __attribute__((ext_vector_type(4))) unsigned short us4;

// ---- LDS layout (bytes). All "planes" are bf16, XOR-swizzled byte^=((row&7)<<4).
#define XHI 0u          // x hi   [64][256] bf16, row stride 512B
#define XLO 32768u      // x lo
#define GHI 65536u      // rh / scratch hi [64][128], row stride 256B
#define GLO 81920u
#define H1HI 98304u     // h1 hi [64][128]
#define H1LO 114688u
#define SHI 131072u     // h2 hi [64][128]
#define SLO 147456u
#define LDS_TOTAL 163840

// ---- workspace layout (bytes)
#define WS_LFRAG 0                      // 2 x 1KB L fragments (hi, lo)
#define WS_W1G   4096                   // 16nt*12ks*2*1024 = 393216
#define WS_W1C   (WS_W1G + 393216)      // 8nt*12ks*2*1024 = 196608
#define WS_W2G   (WS_W1C + 196608)      // 16nt*8ks*2*1024 = 262144
#define WS_W2C   (WS_W2G + 262144)      // 8nt*8ks*2*1024 = 131072

__device__ __forceinline__ unsigned short f2bf(float x) {
    unsigned u = __float_as_uint(x);
    unsigned r = (u + 0x7fffu + ((u >> 16) & 1u)) >> 16;
    return (unsigned short)r;
}
__device__ __forceinline__ float bf2f(unsigned short h) {
    return __uint_as_float(((unsigned)h) << 16);
}
__device__ __forceinline__ f32x4 mfma16(bf8 a, bf8 b, f32x4 c) {
    return __builtin_amdgcn_mfma_f32_16x16x32_bf16(a, b, c, 0, 0, 0);
}

// one K=32 step of the main GEMM for one wave: 2 M-tiles x NNT N-tiles, split-bf16 (3 mfma)
template<int NNT>
__device__ __forceinline__ void kstep(const char* sm, unsigned hiOff, unsigned loOff, unsigned RS,
                                      unsigned s, const char* wb, unsigned NK, unsigned ks,
                                      unsigned t0, unsigned l, unsigned wi, f32x4* acc) {
    const unsigned lrow = l & 15u, lk = l >> 4;
    const unsigned kb = s * 64u + lk * 16u;
    const unsigned row0 = wi * 16u + lrow;
    const unsigned row1 = row0 + 32u;
    const unsigned sw = (lrow & 7u) << 4;
    const bf8 a0h = *(const bf8*)(sm + hiOff + row0 * RS + (kb ^ sw));
    const bf8 a0l = *(const bf8*)(sm + loOff + row0 * RS + (kb ^ sw));
    const bf8 a1h = *(const bf8*)(sm + hiOff + row1 * RS + (kb ^ sw));
    const bf8 a1l = *(const bf8*)(sm + loOff + row1 * RS + (kb ^ sw));
#pragma unroll
    for (int i = 0; i < NNT; ++i) {
        unsigned nt = t0 + (unsigned)(i & 1) + (unsigned)(i >> 1) * 8u;
        const char* wp = wb + ((size_t)(nt * NK + ks) * 2048u) + l * 16u;
        const bf8 bh = *(const bf8*)(wp);
        const bf8 bl = *(const bf8*)(wp + 1024);
        f32x4 a = acc[i];
        a = mfma16(a0h, bh, a);
        a = mfma16(a0l, bh, a);
        a = mfma16(a0h, bl, a);
        acc[i] = a;
        f32x4 b = acc[NNT + i];
        b = mfma16(a1h, bh, b);
        b = mfma16(a1l, bh, b);
        b = mfma16(a1h, bl, b);
        acc[NNT + i] = b;
    }
}

// Laplacian aggregation on a C-fragment: D = L @ pre  (split bf16, 3 mfma, no lane moves)
__device__ __forceinline__ f32x4 agg3(bf8 Lhi, bf8 Llo, f32x4 p) {
    bf8 Bh = {0, 0, 0, 0, 0, 0, 0, 0};
    bf8 Bl = {0, 0, 0, 0, 0, 0, 0, 0};
#pragma unroll
    for (int q = 0; q < 4; ++q) {
        unsigned short h = f2bf(p[q]);
        Bh[q] = (short)h;
        Bl[q] = (short)f2bf(p[q] - bf2f(h));
    }
    f32x4 d = {0.f, 0.f, 0.f, 0.f};
    d = mfma16(Lhi, Bh, d);
    d = mfma16(Lhi, Bl, d);
    d = mfma16(Llo, Bh, d);
    return d;
}

__device__ __forceinline__ float plane_rd(const char* sm, unsigned hiOff, unsigned loOff,
                                          unsigned RS, unsigned row, unsigned col) {
    unsigned off = row * RS + ((col * 2u) ^ ((row & 7u) << 4));
    return bf2f(*(const unsigned short*)(sm + hiOff + off)) +
           bf2f(*(const unsigned short*)(sm + loOff + off));
}
__device__ __forceinline__ void plane_wr(char* sm, unsigned hiOff, unsigned loOff,
                                         unsigned RS, unsigned row, unsigned col, float v) {
    unsigned off = row * RS + ((col * 2u) ^ ((row & 7u) << 4));
    unsigned short h = f2bf(v);
    *(unsigned short*)(sm + hiOff + off) = h;
    *(unsigned short*)(sm + loOff + off) = f2bf(v - bf2f(h));
}

__device__ __forceinline__ float fast_sigm(float x) { return 1.0f / (1.0f + __expf(-x)); }
__device__ __forceinline__ float fast_tanh(float x) {
    x = fminf(fmaxf(x, -15.f), 15.f);
    float e = __expf(2.0f * x);
    return (e - 1.0f) / (e + 1.0f);
}

// ---------------- prep: Laplacian fragments ----------------
__global__ void tgcn_prep_L(const float* __restrict__ adj, char* __restrict__ ws) {
    __shared__ float d[16];
    __shared__ float Lm[16][16];
    int tid = threadIdx.x;
    if (tid < 16) {
        float rs = 1.0f;
        for (int j = 0; j < 16; ++j) rs += adj[tid * 16 + j];
        d[tid] = 1.0f / sqrtf(rs);
    }
    __syncthreads();
    if (tid < 256) {
        int i = tid >> 4, j = tid & 15;
        Lm[i][j] = (adj[j * 16 + i] + (i == j ? 1.0f : 0.0f)) * d[i] * d[j];
    }
    __syncthreads();
    if (tid < 128) {
        int h = tid >> 6, ll = tid & 63;
        int a = ll & 15, g = ll >> 4;
        bf8 f = {0, 0, 0, 0, 0, 0, 0, 0};
        // k-permutation: slot (lg, j<4) represents node 4*lg+j (consistent with agg3's B pack)
        for (int j = 0; j < 4; ++j) {
            float v = Lm[a][4 * g + j];
            unsigned short hi = f2bf(v);
            f[j] = (short)(h == 0 ? hi : f2bf(v - bf2f(hi)));
        }
        *(bf8*)(ws + WS_LFRAG + h * 1024 + ll * 16) = f;
    }
}

// ---------------- prep: weight fragment packing (hi/lo bf16) ----------------
__global__ void tgcn_prep_W(const float* __restrict__ w1g, const float* __restrict__ w1c,
                            const float* __restrict__ w2g, const float* __restrict__ w2c,
                            char* __restrict__ ws) {
    int gid = blockIdx.x * 256 + threadIdx.x;  // 480 frags * 64 lanes = 30720
    if (gid >= 30720) return;
    int fid = gid >> 6, l = gid & 63;
    const float* src; char* dst; int NK, N, nt, ks;
    if (fid < 192)      { src = w1g; dst = ws + WS_W1G; NK = 12; N = 256; nt = fid / 12; ks = fid % 12; }
    else if (fid < 288) { int f = fid - 192; src = w1c; dst = ws + WS_W1C; NK = 12; N = 128; nt = f / 12; ks = f % 12; }
    else if (fid < 416) { int f = fid - 288; src = w2g; dst = ws + WS_W2G; NK = 8;  N = 256; nt = f / 8;  ks = f % 8; }
    else                { int f = fid - 416; src = w2c; dst = ws + WS_W2C; NK = 8;  N = 128; nt = f / 8;  ks = f % 8; }
    int col = nt * 16 + (l & 15);
    int kbase = ks * 32 + (l >> 4) * 8;
    bf8 hi, lo;
#pragma unroll
    for (int j = 0; j < 8; ++j) {
        float v = src[(size_t)(kbase + j) * N + col];
        unsigned short h = f2bf(v);
        hi[j] = (short)h;
        lo[j] = (short)f2bf(v - bf2f(h));
    }
    char* base = dst + ((size_t)(nt * NK + ks) * 2048) + l * 16;
    *(bf8*)(base) = hi;
    *(bf8*)(base + 1024) = lo;
}

// ---------------- main fused kernel ----------------
__global__ __launch_bounds__(512, 2) void tgcn_main(
    const float* __restrict__ feat, const char* __restrict__ ws,
    const float* __restrict__ b1g, const float* __restrict__ b2g,
    const float* __restrict__ bng, const float* __restrict__ bnb,
    const float* __restrict__ bnm, const float* __restrict__ bnv,
    const float* __restrict__ fcw, const float* __restrict__ fcb,
    float* __restrict__ out) {
    extern __shared__ char sm[];
    const int tid = threadIdx.x;
    const int b0 = blockIdx.x * 4;
    const unsigned l = (unsigned)tid & 63u, w = (unsigned)tid >> 6;
    const unsigned wi = w & 1u, wj = w >> 1, t0 = 2u * wj;
    const unsigned lrow = l & 15u, lg = l >> 4;

    const bf8 Lhi = *(const bf8*)(ws + WS_LFRAG + l * 16u);
    const bf8 Llo = *(const bf8*)(ws + WS_LFRAG + 1024u + l * 16u);

    float bias1[4], bias2[4];
#pragma unroll
    for (int i = 0; i < 4; ++i) {
        unsigned nt = t0 + (unsigned)(i & 1) + (unsigned)(i >> 1) * 8u;
        bias1[i] = b1g[nt * 16u + lrow];
        bias2[i] = b2g[nt * 16u + lrow];
    }

    // zero h1 + h2 plane regions (65536 B starting at H1HI)
    {
        const f32x4 z = {0.f, 0.f, 0.f, 0.f};
#pragma unroll
        for (int p = 0; p < 8; ++p)
            *(f32x4*)(sm + H1HI + (unsigned)(tid + p * 512) * 16u) = z;
    }

    const char* wsW1G = ws + WS_W1G;
    const char* wsW1C = ws + WS_W1C;
    const char* wsW2G = ws + WS_W2G;
    const char* wsW2C = ws + WS_W2C;
    const f32x4 zf = {0.f, 0.f, 0.f, 0.f};

    for (int t = 0; t < 5; ++t) {
        // ---- stage x -> X hi/lo planes (swizzled)
        {
            f32x4 v[8];
#pragma unroll
            for (int p = 0; p < 8; ++p) {
                int e = tid + p * 512;
                int row = e >> 6, c4 = (e & 63) << 2;
                size_t gi = (((size_t)(b0 + (row >> 4)) * 5 + t) * 16 + (row & 15)) * 256 + c4;
                v[p] = *(const f32x4*)(feat + gi);
            }
#pragma unroll
            for (int p = 0; p < 8; ++p) {
                int e = tid + p * 512;
                int row = e >> 6, c4 = (e & 63) << 2;
                unsigned off = (unsigned)row * 512u + (((unsigned)c4 * 2u) ^ (((unsigned)row & 7u) << 4));
                us4 hi, lo;
#pragma unroll
                for (int q = 0; q < 4; ++q) {
                    unsigned short h = f2bf(v[p][q]);
                    hi[q] = h;
                    lo[q] = f2bf(v[p][q] - bf2f(h));
                }
                *(us4*)(sm + XHI + off) = hi;
                *(us4*)(sm + XLO + off) = lo;
            }
        }
        __syncthreads();  // b1

        // ---- gates1: [x | h1] @ w1g, K=384, N=256
        f32x4 acc[8];
        f32x4 acc2[4];
        float u1[2][2][4];
#pragma unroll
        for (int i = 0; i < 8; ++i) acc[i] = zf;
#pragma unroll
        for (int ks = 0; ks < 12; ++ks) {
            if (ks < 8) kstep<4>(sm, XHI, XLO, 512u, (unsigned)ks, wsW1G, 12u, (unsigned)ks, t0, l, wi, acc);
            else        kstep<4>(sm, H1HI, H1LO, 256u, (unsigned)(ks - 8), wsW1G, 12u, (unsigned)ks, t0, l, wi, acc);
        }
#pragma unroll
        for (int m2 = 0; m2 < 2; ++m2) {
#pragma unroll
            for (int i = 0; i < 4; ++i) {
                f32x4 g = agg3(Lhi, Llo, acc[m2 * 4 + i]);
                unsigned nt = t0 + (unsigned)(i & 1) + (unsigned)(i >> 1) * 8u;
                unsigned colg = nt * 16u + lrow;
#pragma unroll
                for (int q = 0; q < 4; ++q) {
                    float s = fast_sigm(g[q] + bias1[i]);
                    unsigned row = (wi + 2u * m2) * 16u + lg * 4u + q;
                    if (i < 2) {  // r tile -> rh = r*h1 into G planes
                        float h1v = plane_rd(sm, H1HI, H1LO, 256u, row, colg);
                        plane_wr(sm, GHI, GLO, 256u, row, colg, s * h1v);
                    } else {      // u tile -> registers
                        u1[m2][i - 2][q] = s;
                    }
                }
            }
        }
        __syncthreads();  // b2

        // ---- cand1: [x | rh] @ w1c, K=384, N=128; h1 update
#pragma unroll
        for (int i = 0; i < 4; ++i) acc2[i] = zf;
#pragma unroll
        for (int ks = 0; ks < 12; ++ks) {
            if (ks < 8) kstep<2>(sm, XHI, XLO, 512u, (unsigned)ks, wsW1C, 12u, (unsigned)ks, t0, l, wi, acc2);
            else        kstep<2>(sm, GHI, GLO, 256u, (unsigned)(ks - 8), wsW1C, 12u, (unsigned)ks, t0, l, wi, acc2);
        }
#pragma unroll
        for (int m2 = 0; m2 < 2; ++m2) {
#pragma unroll
            for (int i = 0; i < 2; ++i) {
                f32x4 c = agg3(Lhi, Llo, acc2[m2 * 2 + i]);
                unsigned col = (t0 + (unsigned)i) * 16u + lrow;
#pragma unroll
                for (int q = 0; q < 4; ++q) {
                    float cv = fast_tanh(c[q]);
                    float u = u1[m2][i][q];
                    unsigned row = (wi + 2u * m2) * 16u + lg * 4u + q;
                    float hv = plane_rd(sm, H1HI, H1LO, 256u, row, col);
                    plane_wr(sm, H1HI, H1LO, 256u, row, col, u * hv + (1.0f - u) * cv);
                }
            }
        }
        __syncthreads();  // b3

        // ---- gates2: [h1 | h2] @ w2g, K=256, N=256
#pragma unroll
        for (int i = 0; i < 8; ++i) acc[i] = zf;
#pragma unroll
        for (int ks = 0; ks < 8; ++ks) {
            if (ks < 4) kstep<4>(sm, H1HI, H1LO, 256u, (unsigned)ks, wsW2G, 8u, (unsigned)ks, t0, l, wi, acc);
            else        kstep<4>(sm, SHI, SLO, 256u, (unsigned)(ks - 4), wsW2G, 8u, (unsigned)ks, t0, l, wi, acc);
        }
#pragma unroll
        for (int m2 = 0; m2 < 2; ++m2) {
#pragma unroll
            for (int i = 0; i < 4; ++i) {
                f32x4 g = agg3(Lhi, Llo, acc[m2 * 4 + i]);
                unsigned nt = t0 + (unsigned)(i & 1) + (unsigned)(i >> 1) * 8u;
                unsigned colg = nt * 16u + lrow;
#pragma unroll
                for (int q = 0; q < 4; ++q) {
                    float s = fast_sigm(g[q] + bias2[i]);
                    unsigned row = (wi + 2u * m2) * 16u + lg * 4u + q;
                    if (i < 2) {  // rh2 = r2*h2 into G planes
                        float h2v = plane_rd(sm, SHI, SLO, 256u, row, colg);
                        plane_wr(sm, GHI, GLO, 256u, row, colg, s * h2v);
                    } else {
                        u1[m2][i - 2][q] = s;
                    }
                }
            }
        }
        __syncthreads();  // b4

        // ---- cand2: [h1 | rh2] @ w2c, K=256, N=128; h2 update
#pragma unroll
        for (int i = 0; i < 4; ++i) acc2[i] = zf;
#pragma unroll
        for (int ks = 0; ks < 8; ++ks) {
            if (ks < 4) kstep<2>(sm, H1HI, H1LO, 256u, (unsigned)ks, wsW2C, 8u, (unsigned)ks, t0, l, wi, acc2);
            else        kstep<2>(sm, GHI, GLO, 256u, (unsigned)(ks - 4), wsW2C, 8u, (unsigned)ks, t0, l, wi, acc2);
        }
#pragma unroll
        for (int m2 = 0; m2 < 2; ++m2) {
#pragma unroll
            for (int i = 0; i < 2; ++i) {
                f32x4 c = agg3(Lhi, Llo, acc2[m2 * 2 + i]);
                unsigned col = (t0 + (unsigned)i) * 16u + lrow;
#pragma unroll
                for (int q = 0; q < 4; ++q) {
                    float cv = fast_tanh(c[q]);
                    float u = u1[m2][i][q];
                    unsigned row = (wi + 2u * m2) * 16u + lg * 4u + q;
                    float hv = plane_rd(sm, SHI, SLO, 256u, row, col);
                    plane_wr(sm, SHI, SLO, 256u, row, col, u * hv + (1.0f - u) * cv);
                }
            }
        }
        __syncthreads();  // b5
    }

    // ---- head: BN -> ReLU -> FC(2048->2) from h2 (S planes)
    {
        int row = tid >> 3, cb = tid & 7;
        int a = row & 15;
        unsigned c0 = (unsigned)cb * 16u;
        unsigned sw = ((unsigned)row & 7u) << 4;
        unsigned base = (unsigned)row * 256u;
        unsigned o0 = base + ((c0 * 2u) ^ sw);
        unsigned o1 = base + ((c0 * 2u + 16u) ^ sw);
        bf8 hA = *(const bf8*)(sm + SHI + o0);
        bf8 hB = *(const bf8*)(sm + SHI + o1);
        bf8 lA = *(const bf8*)(sm + SLO + o0);
        bf8 lB = *(const bf8*)(sm + SLO + o1);
        int k2 = a * 128 + (int)c0;
        float p0 = 0.f, p1 = 0.f;
#pragma unroll
        for (int j = 0; j < 16; ++j) {
            unsigned short hh = (unsigned short)(j < 8 ? hA[j] : hB[j - 8]);
            unsigned short ll = (unsigned short)(j < 8 ? lA[j] : lB[j - 8]);
            float v = bf2f(hh) + bf2f(ll);
            int k = k2 + j;
            float x = bng[k] * (v - bnm[k]) * rsqrtf(bnv[k] + 1e-5f) + bnb[k];
            x = fmaxf(x, 0.f);
            p0 += x * fcw[2 * k];
            p1 += x * fcw[2 * k + 1];
        }
        p0 += __shfl_down(p0, 4, 8); p0 += __shfl_down(p0, 2, 8); p0 += __shfl_down(p0, 1, 8);
        p1 += __shfl_down(p1, 4, 8); p1 += __shfl_down(p1, 2, 8); p1 += __shfl_down(p1, 1, 8);
        if ((tid & 7) == 0) {
            ((float*)(sm + GHI))[row * 2] = p0;
            ((float*)(sm + GHI))[row * 2 + 1] = p1;
        }
        __syncthreads();
        if (tid < 8) {
            int b = tid >> 1, o = tid & 1;
            float s = fcb[o];
#pragma unroll
            for (int aa = 0; aa < 16; ++aa) s += ((const float*)(sm + GHI))[(b * 16 + aa) * 2 + o];
            out[(size_t)(b0 + b) * 2 + o] = s;
        }
    }
}

extern "C" void kernel_launch(void* const* d_in, const int* in_sizes, int n_in,
                              void* d_out, int out_size, void* d_ws, size_t ws_size,
                              hipStream_t stream) {
    const float* feat = (const float*)d_in[0];
    const float* adj  = (const float*)d_in[1];
    const float* w1g  = (const float*)d_in[2];
    const float* b1g  = (const float*)d_in[3];
    const float* w1c  = (const float*)d_in[4];
    const float* w2g  = (const float*)d_in[5];
    const float* b2g  = (const float*)d_in[6];
    const float* w2c  = (const float*)d_in[7];
    const float* bng  = (const float*)d_in[8];
    const float* bnb  = (const float*)d_in[9];
    const float* bnm  = (const float*)d_in[10];
    const float* bnv  = (const float*)d_in[11];
    const float* fcw  = (const float*)d_in[12];
    const float* fcb  = (const float*)d_in[13];
    float* out = (float*)d_out;
    char* ws = (char*)d_ws;

    int B = in_sizes[0] / (5 * 16 * 256);  // 4096

    hipFuncSetAttribute((const void*)tgcn_main,
                        hipFuncAttributeMaxDynamicSharedMemorySize, LDS_TOTAL);

    tgcn_prep_L<<<1, 256, 0, stream>>>(adj, ws);
    tgcn_prep_W<<<120, 256, 0, stream>>>(w1g, w1c, w2g, w2c, ws);
    tgcn_main<<<B / 4, 512, LDS_TOTAL, stream>>>(feat, ws, b1g, b2g,
                                                 bng, bnb, bnm, bnv, fcw, fcb, out);
}